// Round 5
// baseline (800.022 us; speedup 1.0000x reference)
//
#include <hip/hip_runtime.h>
#include <hip/hip_bf16.h>

typedef __hip_bfloat16 bf16;
typedef __attribute__((ext_vector_type(8))) short short8;
typedef __attribute__((ext_vector_type(4))) float f32x4;

#define AS1 __attribute__((address_space(1)))
#define AS3 __attribute__((address_space(3)))

__device__ __forceinline__ void gload_lds16(const bf16* gp, bf16* lp) {
  __builtin_amdgcn_global_load_lds((const AS1 void*)gp, (AS3 void*)lp, 16, 0, 0);
}

__device__ __forceinline__ float fast_exp2(float x) {
#if __has_builtin(__builtin_amdgcn_exp2f)
  return __builtin_amdgcn_exp2f(x);
#else
  return exp2f(x);
#endif
}

__device__ __forceinline__ void store_c(bf16* C, size_t idx, float v) { C[idx] = __float2bfloat16(v); }
__device__ __forceinline__ void store_c(float* C, size_t idx, float v) { C[idx] = v; }

struct __align__(8) b16x4 { bf16 a, b, c, d; };

// ---------------------------------------------------------------------------
// fp32 -> bf16 elementwise convert (n multiple of 1024)
// ---------------------------------------------------------------------------
__global__ void cvt_f32_bf16(const float* __restrict__ in, bf16* __restrict__ out) {
  const int i = (blockIdx.x * 256 + threadIdx.x) * 4;
  const float4 v = *(const float4*)(in + i);
  out[i + 0] = __float2bfloat16(v.x);
  out[i + 1] = __float2bfloat16(v.y);
  out[i + 2] = __float2bfloat16(v.z);
  out[i + 3] = __float2bfloat16(v.w);
}

// ---------------------------------------------------------------------------
// All 8 weight transposes (fp32 [R][C] -> bf16 [C][R]) in ONE kernel.
// ---------------------------------------------------------------------------
struct PrepArgs {
  const float* src[8];
  bf16* dst[8];
  int R[8], C[8], cum[8];
};

__global__ void prep_kernel(PrepArgs a) {
  __shared__ bf16 t[32][33];
  const int blk = blockIdx.x;
  int e = 0;
  while (e < 7 && blk >= a.cum[e]) ++e;
  const int lt = blk - (e ? a.cum[e - 1] : 0);
  const int R = a.R[e], C = a.C[e];
  const int tpr = C >> 5;
  const int bx = lt % tpr, by = lt / tpr;
  const float* in = a.src[e];
  bf16* out = a.dst[e];
  const int c0 = bx * 32, r0 = by * 32;
  const int tx = threadIdx.x, ty = threadIdx.y;
  for (int i = 0; i < 4; ++i)
    t[ty + 8 * i][tx] = __float2bfloat16(in[(size_t)(r0 + ty + 8 * i) * C + c0 + tx]);
  __syncthreads();
  for (int i = 0; i < 4; ++i)
    out[(size_t)(c0 + ty + 8 * i) * R + r0 + tx] = t[tx][ty + 8 * i];
}

// ---------------------------------------------------------------------------
// Generic bf16 GEMM, C = A @ B with B supplied transposed (Bt[N][K]).
// m97 structure. MODE compile-time (r5 lesson: runtime mode -> scratch spill).
// MODE 4: cn<1024 -> latcat; cn>=1024 -> k_rope with RoPE FUSED in-register
// (r4: rope pair (i,i+32) = acc tiles (nt,nt+2) same lane; n0>=1024 is
// block-uniform; angle = (row&2047) * 10000^(-i/32), i0=l16, i1=16+l16).
// ---------------------------------------------------------------------------
template <typename CT, int MODE>
__global__ void gemm_bt(const bf16* __restrict__ A, int lda,
                        const bf16* __restrict__ Bt,
                        CT* __restrict__ C, bf16* __restrict__ C2, int ldc,
                        int K)
{
  __shared__ __align__(16) bf16 As[128 * 32];
  __shared__ __align__(16) bf16 Bs[128 * 32];
  const int tid  = threadIdx.x;
  const int wave = tid >> 6, lane = tid & 63;
  const int quad = lane >> 4, l16 = lane & 15;
  const int m0 = blockIdx.y * 128, n0 = blockIdx.x * 128;
  const int wm = (wave >> 1) * 64, wn = (wave & 1) * 64;

  f32x4 acc[4][4];
#pragma unroll
  for (int i = 0; i < 4; ++i)
#pragma unroll
    for (int j = 0; j < 4; ++j) acc[i][j] = (f32x4){0.f, 0.f, 0.f, 0.f};

  const int r1  = tid >> 2;
  const int ks1 = (tid & 3) * 8;

  for (int k0 = 0; k0 < K; k0 += 32) {
    gload_lds16(A  + (size_t)(m0 + r1)      * lda + k0 + ks1, &As[tid * 8]);
    gload_lds16(A  + (size_t)(m0 + r1 + 64) * lda + k0 + ks1, &As[(tid + 256) * 8]);
    gload_lds16(Bt + (size_t)(n0 + r1)      * K   + k0 + ks1, &Bs[tid * 8]);
    gload_lds16(Bt + (size_t)(n0 + r1 + 64) * K   + k0 + ks1, &Bs[(tid + 256) * 8]);
    __syncthreads();

    short8 af[4], bf_[4];
#pragma unroll
    for (int mt = 0; mt < 4; ++mt)
      af[mt] = *(const short8*)&As[(wm + mt * 16 + l16) * 32 + quad * 8];
#pragma unroll
    for (int nt = 0; nt < 4; ++nt)
      bf_[nt] = *(const short8*)&Bs[(wn + nt * 16 + l16) * 32 + quad * 8];
#pragma unroll
    for (int mt = 0; mt < 4; ++mt)
#pragma unroll
      for (int nt = 0; nt < 4; ++nt)
        acc[mt][nt] = __builtin_amdgcn_mfma_f32_16x16x32_bf16(af[mt], bf_[nt], acc[mt][nt], 0, 0, 0);
    __syncthreads();
  }

  if (MODE == 0) {
#pragma unroll
    for (int mt = 0; mt < 4; ++mt) {
      const int row = m0 + wm + mt * 16 + quad * 4;
#pragma unroll
      for (int nt = 0; nt < 4; ++nt) {
        const int cn = n0 + wn + nt * 16 + l16;
        const f32x4 v = acc[mt][nt];
#pragma unroll
        for (int r = 0; r < 4; ++r)
          store_c(C, (size_t)(row + r) * ldc + cn, v[r]);
      }
    }
  } else if (MODE == 4) {
    if (n0 < 1024) {
      // latcat path (whole block has cn < 1024)
#pragma unroll
      for (int mt = 0; mt < 4; ++mt) {
        const int row = m0 + wm + mt * 16 + quad * 4;
#pragma unroll
        for (int nt = 0; nt < 4; ++nt) {
          const int cn = n0 + wn + nt * 16 + l16;
          const f32x4 v = acc[mt][nt];
#pragma unroll
          for (int r = 0; r < 4; ++r)
            store_c(C, (size_t)(row + r) * 1024 + cn, v[r]);
        }
      }
    } else {
      // k_rope path with fused RoPE (whole block has cn >= 1024)
      const float CF = 0.41524101186092029f;            // log2(10000)/32
      const float inv0 = fast_exp2(-(float)l16 * CF);
      const float inv1 = fast_exp2(-(float)(16 + l16) * CF);
#pragma unroll
      for (int mt = 0; mt < 4; ++mt) {
        const int row = m0 + wm + mt * 16 + quad * 4;
        f32x4 w[4];
#pragma unroll
        for (int nt = 0; nt < 4; ++nt) w[nt] = acc[mt][nt];
#pragma unroll
        for (int r = 0; r < 4; ++r) {
          const int s = (row + r) & 2047;
          const float a0 = (float)s * inv0, a1 = (float)s * inv1;
          const float c0 = cosf(a0), s0 = sinf(a0);
          const float c1 = cosf(a1), s1 = sinf(a1);
          const float x1a = w[0][r], x2a = w[2][r];
          const float x1b = w[1][r], x2b = w[3][r];
          w[0][r] = x1a * c0 - x2a * s0;
          w[2][r] = x2a * c0 + x1a * s0;
          w[1][r] = x1b * c1 - x2b * s1;
          w[3][r] = x2b * c1 + x1b * s1;
        }
#pragma unroll
        for (int nt = 0; nt < 4; ++nt) {
          const int cn2 = n0 + wn + nt * 16 + l16 - 1024;
          const int g = ((cn2 >> 6) << 7) + 64 + (cn2 & 63);
#pragma unroll
          for (int r = 0; r < 4; ++r)
            C2[(size_t)(row + r) * 2048 + g] = __float2bfloat16(w[nt][r]);
        }
      }
    }
  }
}

// ---------------------------------------------------------------------------
// Fused up-projection GEMM: k_nope+vT (N=3072, from kv_latent) and
// q-interleave (N=2048, from q_latent) in ONE launch. K=512, lda=1024.
// grid = (40, 32): x<24 -> k_nope/vT, x>=24 -> q-interleave.
// q_rope (n0>=1024 blocks of is2) gets RoPE fused in-register (r4).
// ---------------------------------------------------------------------------
__global__ void gemm_up_fused(const bf16* __restrict__ latcat,
                              const bf16* __restrict__ wtUP,
                              const bf16* __restrict__ wtQcat,
                              bf16* __restrict__ vT, bf16* __restrict__ kfull,
                              bf16* __restrict__ qfull)
{
  const bool is2 = (blockIdx.x >= 24);
  const bf16* A  = latcat + (is2 ? 512 : 0);
  const bf16* Bt = is2 ? wtQcat : wtUP;
  const int n0 = (is2 ? (int)blockIdx.x - 24 : (int)blockIdx.x) * 128;
  const int K = 512, lda = 1024;

  __shared__ __align__(16) bf16 As[128 * 32];
  __shared__ __align__(16) bf16 Bs[128 * 32];
  const int tid  = threadIdx.x;
  const int wave = tid >> 6, lane = tid & 63;
  const int quad = lane >> 4, l16 = lane & 15;
  const int m0 = blockIdx.y * 128;
  const int wm = (wave >> 1) * 64, wn = (wave & 1) * 64;

  f32x4 acc[4][4];
#pragma unroll
  for (int i = 0; i < 4; ++i)
#pragma unroll
    for (int j = 0; j < 4; ++j) acc[i][j] = (f32x4){0.f, 0.f, 0.f, 0.f};

  const int r1  = tid >> 2;
  const int ks1 = (tid & 3) * 8;

  for (int k0 = 0; k0 < K; k0 += 32) {
    gload_lds16(A  + (size_t)(m0 + r1)      * lda + k0 + ks1, &As[tid * 8]);
    gload_lds16(A  + (size_t)(m0 + r1 + 64) * lda + k0 + ks1, &As[(tid + 256) * 8]);
    gload_lds16(Bt + (size_t)(n0 + r1)      * K   + k0 + ks1, &Bs[tid * 8]);
    gload_lds16(Bt + (size_t)(n0 + r1 + 64) * K   + k0 + ks1, &Bs[(tid + 256) * 8]);
    __syncthreads();

    short8 af[4], bf_[4];
#pragma unroll
    for (int mt = 0; mt < 4; ++mt)
      af[mt] = *(const short8*)&As[(wm + mt * 16 + l16) * 32 + quad * 8];
#pragma unroll
    for (int nt = 0; nt < 4; ++nt)
      bf_[nt] = *(const short8*)&Bs[(wn + nt * 16 + l16) * 32 + quad * 8];
#pragma unroll
    for (int mt = 0; mt < 4; ++mt)
#pragma unroll
      for (int nt = 0; nt < 4; ++nt)
        acc[mt][nt] = __builtin_amdgcn_mfma_f32_16x16x32_bf16(af[mt], bf_[nt], acc[mt][nt], 0, 0, 0);
    __syncthreads();
  }

  if (is2) {
    if (n0 < 1024) {
      // q_nope half: plain interleave store
#pragma unroll
      for (int mt = 0; mt < 4; ++mt) {
        const int row = m0 + wm + mt * 16 + quad * 4;
#pragma unroll
        for (int nt = 0; nt < 4; ++nt) {
          const int cn = n0 + wn + nt * 16 + l16;
          const int g = (((cn >> 6) & 15) << 7) + ((cn >> 10) << 6) + (cn & 63);
          const f32x4 v = acc[mt][nt];
#pragma unroll
          for (int r = 0; r < 4; ++r)
            qfull[(size_t)(row + r) * 2048 + g] = __float2bfloat16(v[r]);
        }
      }
    } else {
      // q_rope half: fuse RoPE before interleave store
      const float CF = 0.41524101186092029f;            // log2(10000)/32
      const float inv0 = fast_exp2(-(float)l16 * CF);
      const float inv1 = fast_exp2(-(float)(16 + l16) * CF);
#pragma unroll
      for (int mt = 0; mt < 4; ++mt) {
        const int row = m0 + wm + mt * 16 + quad * 4;
        f32x4 w[4];
#pragma unroll
        for (int nt = 0; nt < 4; ++nt) w[nt] = acc[mt][nt];
#pragma unroll
        for (int r = 0; r < 4; ++r) {
          const int s = (row + r) & 2047;
          const float a0 = (float)s * inv0, a1 = (float)s * inv1;
          const float c0 = cosf(a0), s0 = sinf(a0);
          const float c1 = cosf(a1), s1 = sinf(a1);
          const float x1a = w[0][r], x2a = w[2][r];
          const float x1b = w[1][r], x2b = w[3][r];
          w[0][r] = x1a * c0 - x2a * s0;
          w[2][r] = x2a * c0 + x1a * s0;
          w[1][r] = x1b * c1 - x2b * s1;
          w[3][r] = x2b * c1 + x1b * s1;
        }
#pragma unroll
        for (int nt = 0; nt < 4; ++nt) {
          const int cn = n0 + wn + nt * 16 + l16;
          const int g = (((cn >> 6) & 15) << 7) + ((cn >> 10) << 6) + (cn & 63);
#pragma unroll
          for (int r = 0; r < 4; ++r)
            qfull[(size_t)(row + r) * 2048 + g] = __float2bfloat16(w[nt][r]);
        }
      }
    }
  } else {
#pragma unroll
    for (int mt = 0; mt < 4; ++mt) {
      const int row = m0 + wm + mt * 16 + quad * 4;
#pragma unroll
      for (int nt = 0; nt < 4; ++nt) {
        const int cn = n0 + wn + nt * 16 + l16;
        const f32x4 v = acc[mt][nt];
        if (cn < 1024) {
          const int g = ((cn >> 6) << 7) + (cn & 63);
#pragma unroll
          for (int r = 0; r < 4; ++r)
            kfull[(size_t)(row + r) * 2048 + g] = __float2bfloat16(v[r]);
        } else {
          const int cn2 = cn - 1024;
          const int bb = row >> 11, s0 = row & 2047;
          b16x4 pk;
          pk.a = __float2bfloat16(v[0]); pk.b = __float2bfloat16(v[1]);
          pk.c = __float2bfloat16(v[2]); pk.d = __float2bfloat16(v[3]);
          *(b16x4*)(vT + ((size_t)(bb * 2048 + cn2)) * 2048 + s0) = pk;
        }
      }
    }
  }
}

// ---------------------------------------------------------------------------
// Flash attention v7 (causal) — reverted to the r1 version (best measured:
// 68.4 us). 32 q-rows per wave (128-q blocks), 64-key tiles, XOR-swizzled
// K/V/P LDS, register prefetch, 2 barriers/tile. Grid (32 bh, 16 qt) = 512
// blocks, all resident. r3 lesson: cross-block merge via device-scope
// acquire/release nukes per-XCD L2 (buffer_inv) -> never again in hot path.
// ---------------------------------------------------------------------------
__global__ __launch_bounds__(256, 2) void attn7_kernel(
    const bf16* __restrict__ Q, const bf16* __restrict__ Kf,
    const bf16* __restrict__ VT, bf16* __restrict__ Y)
{
  __shared__ __align__(16) bf16 Ks[64 * 128];    // [key][d], XOR-swizzled
  __shared__ __align__(16) bf16 VTs[128 * 64];   // [d][key], XOR-swizzled
  __shared__ __align__(16) bf16 Ps[4 * 32 * 64]; // per-wave P, quad-XOR-swizzled
  const int tid  = threadIdx.x;
  const int wave = tid >> 6, lane = tid & 63;
  const int quad = lane >> 4, l16 = lane & 15;
  const int bh = blockIdx.x;                     // fastest-varying -> L2 locality
  const int yy = blockIdx.y;
  const int aa = yy & 7;
  const int qt = (yy >> 3) ? (15 - aa) : aa;
  const size_t kqbase = ((size_t)(bh >> 4) * 2048) * 2048 + (bh & 15) * 128;
  const size_t vtbase = (size_t)bh * 128 * 2048;
  const float C2 = 0.08838834764831845f * 1.4426950408889634f; // scale*log2e
  const float MNEG = -30.0f;

  short8 ones;
#pragma unroll
  for (int i = 0; i < 8; ++i) ones[i] = (short)0x3F80;   // bf16 1.0

  const int krow = tid >> 4, kcol = (tid & 15) * 8;  // K: 4 instr x 16 rows
  const int vrow = tid >> 3, vcol = (tid & 7) * 8;   // VT: 4 instr x 32 rows

  const int q0 = qt * 128;
  const int T = 2 * qt + 2;
  const int wq0 = q0 + wave * 32;                // this wave's first q row
  const int psbase = wave * (32 * 64);

  short8 qf[2][4];
#pragma unroll
  for (int m = 0; m < 2; ++m) {
    const bf16* qp = Q + kqbase + (size_t)(wq0 + m * 16 + l16) * 2048 + quad * 8;
#pragma unroll
    for (int kc = 0; kc < 4; ++kc) qf[m][kc] = *(const short8*)(qp + kc * 32);
  }
  f32x4 o[2][8];
#pragma unroll
  for (int m = 0; m < 2; ++m)
#pragma unroll
    for (int i = 0; i < 8; ++i) o[m][i] = (f32x4){0, 0, 0, 0};
  f32x4 lacc[2];
  lacc[0] = (f32x4){0, 0, 0, 0};
  lacc[1] = (f32x4){0, 0, 0, 0};

  short8 kg[4], vg[4];
#pragma unroll
  for (int i = 0; i < 4; ++i)
    kg[i] = *(const short8*)(Kf + kqbase + (size_t)(krow + i * 16) * 2048 + kcol);
#pragma unroll
  for (int i = 0; i < 4; ++i)
    vg[i] = *(const short8*)(VT + vtbase + (size_t)(vrow + i * 32) * 2048 + vcol);

  for (int t = 0; t < T; ++t) {
    const int k0 = t * 64;
    __syncthreads();                    // all waves done reading prev tile
#pragma unroll
    for (int i = 0; i < 4; ++i) {
      const int rw = krow + i * 16;
      *(short8*)&Ks[rw * 128 + (kcol ^ ((rw & 7) * 8))] = kg[i];
    }
#pragma unroll
    for (int i = 0; i < 4; ++i) {
      const int rw = vrow + i * 32;
      *(short8*)&VTs[rw * 64 + (vcol ^ ((rw & 7) * 8))] = vg[i];
    }
    __syncthreads();                    // tile t visible
    if (t + 1 < T) {                    // prefetch t+1 under compute
      const int kn = k0 + 64;
#pragma unroll
      for (int i = 0; i < 4; ++i)
        kg[i] = *(const short8*)(Kf + kqbase + (size_t)(kn + krow + i * 16) * 2048 + kcol);
#pragma unroll
      for (int i = 0; i < 4; ++i)
        vg[i] = *(const short8*)(VT + vtbase + (size_t)(vrow + i * 32) * 2048 + kn + vcol);
    }

    if (k0 <= wq0 + 31) {               // wave has >=1 unmasked key this tile
      // ---- S = Q K^T (raw scores), both m-tiles share each K fragment ----
      f32x4 sf[2][4];
#pragma unroll
      for (int m = 0; m < 2; ++m)
#pragma unroll
        for (int kt = 0; kt < 4; ++kt) sf[m][kt] = (f32x4){0, 0, 0, 0};
#pragma unroll
      for (int kt = 0; kt < 4; ++kt) {
#pragma unroll
        for (int kc = 0; kc < 4; ++kc) {
          const short8 bfr = *(const short8*)&Ks[(kt * 16 + l16) * 128 +
                                                ((kc * 32 + quad * 8) ^ ((l16 & 7) * 8))];
          sf[0][kt] = __builtin_amdgcn_mfma_f32_16x16x32_bf16(qf[0][kc], bfr, sf[0][kt], 0, 0, 0);
          sf[1][kt] = __builtin_amdgcn_mfma_f32_16x16x32_bf16(qf[1][kc], bfr, sf[1][kt], 0, 0, 0);
        }
      }
      // ---- causal mask (only near the diagonal) ----
#pragma unroll
      for (int m = 0; m < 2; ++m) {
        const int row0m = wq0 + m * 16 + quad * 4;
        if (k0 + 63 > row0m) {
#pragma unroll
          for (int kt = 0; kt < 4; ++kt) {
            const int col = k0 + kt * 16 + l16;
#pragma unroll
            for (int r = 0; r < 4; ++r)
              sf[m][kt][r] = (col > row0m + r) ? -3e38f : sf[m][kt][r];
          }
        }
      }
      // ---- p = exp2(s*C2 - M) -> Ps (quad-XOR swizzle: conflict-free) ----
#pragma unroll
      for (int m = 0; m < 2; ++m)
#pragma unroll
        for (int kt = 0; kt < 4; ++kt)
#pragma unroll
          for (int r = 0; r < 4; ++r) {
            const float p = fast_exp2(__builtin_fmaf(sf[m][kt][r], C2, MNEG));
            const int prow = m * 16 + quad * 4 + r;
            const int pcol = (kt * 16 + l16) ^ (quad * 16);
            Ps[psbase + prow * 64 + pcol] = __float2bfloat16(p);
          }
      asm volatile("s_waitcnt lgkmcnt(0)" ::: "memory");
      // ---- O += P V, l += P*1; each V fragment shared by both m-tiles ----
#pragma unroll
      for (int kc = 0; kc < 2; ++kc) {
        short8 ap[2];
#pragma unroll
        for (int m = 0; m < 2; ++m) {
          const int acol = (kc * 32 + quad * 8) ^ (((l16 >> 2) & 3) * 16);
          ap[m] = *(const short8*)&Ps[psbase + (m * 16 + l16) * 64 + acol];
          lacc[m] = __builtin_amdgcn_mfma_f32_16x16x32_bf16(ap[m], ones, lacc[m], 0, 0, 0);
        }
#pragma unroll
        for (int dt = 0; dt < 8; ++dt) {
          const short8 vb = *(const short8*)&VTs[(dt * 16 + l16) * 64 +
                                                ((kc * 32 + quad * 8) ^ ((l16 & 7) * 8))];
          o[0][dt] = __builtin_amdgcn_mfma_f32_16x16x32_bf16(ap[0], vb, o[0][dt], 0, 0, 0);
          o[1][dt] = __builtin_amdgcn_mfma_f32_16x16x32_bf16(ap[1], vb, o[1][dt], 0, 0, 0);
        }
      }
    }
  }

#pragma unroll
  for (int m = 0; m < 2; ++m) {
    const int row0m = wq0 + m * 16 + quad * 4;
#pragma unroll
    for (int r = 0; r < 4; ++r) {
      const float inv = 1.0f / lacc[m][r];
#pragma unroll
      for (int dt = 0; dt < 8; ++dt)
        Y[kqbase + (size_t)(row0m + r) * 2048 + dt * 16 + l16] =
            __float2bfloat16(o[m][dt][r] * inv);
    }
  }
}

// ---------------------------------------------------------------------------
extern "C" void kernel_launch(void* const* d_in, const int* in_sizes, int n_in,
                              void* d_out, int out_size, void* d_ws, size_t ws_size,
                              hipStream_t stream)
{
  const float* x      = (const float*)d_in[0];
  const float* Wkvd   = (const float*)d_in[1];
  const float* Wqd    = (const float*)d_in[2];
  const float* Wku    = (const float*)d_in[3];
  const float* Wqu    = (const float*)d_in[4];
  const float* Wvu    = (const float*)d_in[5];
  const float* Wropek = (const float*)d_in[6];
  const float* Wropeq = (const float*)d_in[7];
  const float* Wo     = (const float*)d_in[8];

  char* ws = (char*)d_ws;
  size_t off = 0;
  auto alloc = [&](size_t elems) {
    bf16* p = (bf16*)(ws + off);
    off += ((elems * sizeof(bf16) + 255) & ~(size_t)255);
    return p;
  };
  // Region A — dead before attn; ybuf (16 MB) aliases it.
  bf16* wtX    = alloc((size_t)2048 * 2048); // Wkvd^T | Wqd^T | Wropek^T
  bf16* wtUP   = alloc((size_t)3072 * 512);  // Wku^T | Wvu^T
  bf16* wtQcat = alloc((size_t)2048 * 512);  // Wqu^T | Wropeq^T
  bf16* latcat = alloc((size_t)4096 * 1024);
  // end region A (21 MB)
  bf16* wt_o   = alloc((size_t)2048 * 2048);
  bf16* xbf    = alloc((size_t)4096 * 2048);
  bf16* qfull  = alloc((size_t)4096 * 2048);
  bf16* kfull  = alloc((size_t)4096 * 2048);
  bf16* ybuf   = (bf16*)ws;
  bf16* vT     = (bf16*)d_out;
  (void)ws_size; (void)in_sizes; (void)n_in; (void)out_size;

  cvt_f32_bf16<<<8192, 256, 0, stream>>>(x, xbf);

  PrepArgs pa;
  const float* srcs[8] = {Wkvd, Wqd, Wropek, Wku, Wvu, Wqu, Wropeq, Wo};
  bf16* dsts[8] = {wtX, wtX + (size_t)512 * 2048, wtX + (size_t)1024 * 2048,
                   wtUP, wtUP + (size_t)1024 * 512,
                   wtQcat, wtQcat + (size_t)1024 * 512, wt_o};
  const int Rs[8] = {2048, 2048, 2048, 512, 512, 512, 512, 2048};
  const int Cs[8] = {512, 512, 1024, 1024, 2048, 1024, 1024, 2048};
  int cum = 0;
  for (int e = 0; e < 8; ++e) {
    pa.src[e] = srcs[e]; pa.dst[e] = dsts[e]; pa.R[e] = Rs[e]; pa.C[e] = Cs[e];
    cum += (Rs[e] >> 5) * (Cs[e] >> 5);
    pa.cum[e] = cum;
  }
  prep_kernel<<<cum, dim3(32, 8), 0, stream>>>(pa);

  // latcat = x @ [W_kv_d | W_q_d]  AND  k_rope = x @ W_rope_k (RoPE fused)
  gemm_bt<bf16, 4><<<dim3(16, 32), 256, 0, stream>>>(xbf, 2048, wtX, latcat, kfull, 1024, 2048);
  // k_nope+vT AND q-interleave (q_rope RoPE fused), single launch
  gemm_up_fused<<<dim3(40, 32), 256, 0, stream>>>(latcat, wtUP, wtQcat, vT, kfull, qfull);

  attn7_kernel<<<dim3(32, 16), 256, 0, stream>>>(qfull, kfull, vT, ybuf);
  // out = y @ W_o (fp32 store)
  gemm_bt<float, 0><<<dim3(16, 32), 256, 0, stream>>>(ybuf, 2048, wt_o, (float*)d_out, (bf16*)nullptr, 2048, 2048);
}

// Round 6
// 326.939 us; speedup vs baseline: 2.4470x; 2.4470x over previous
//
#include <hip/hip_runtime.h>
#include <hip/hip_bf16.h>

typedef __hip_bfloat16 bf16;
typedef __attribute__((ext_vector_type(8))) short short8;
typedef __attribute__((ext_vector_type(4))) float f32x4;

#define AS1 __attribute__((address_space(1)))
#define AS3 __attribute__((address_space(3)))

__device__ __forceinline__ void gload_lds16(const bf16* gp, bf16* lp) {
  __builtin_amdgcn_global_load_lds((const AS1 void*)gp, (AS3 void*)lp, 16, 0, 0);
}

__device__ __forceinline__ float fast_exp2(float x) {
#if __has_builtin(__builtin_amdgcn_exp2f)
  return __builtin_amdgcn_exp2f(x);
#else
  return exp2f(x);
#endif
}

__device__ __forceinline__ void store_c(bf16* C, size_t idx, float v) { C[idx] = __float2bfloat16(v); }
__device__ __forceinline__ void store_c(float* C, size_t idx, float v) { C[idx] = v; }

struct __align__(8) b16x4 { bf16 a, b, c, d; };

// ---------------------------------------------------------------------------
// fp32 -> bf16 elementwise convert (n multiple of 1024)
// ---------------------------------------------------------------------------
__global__ void cvt_f32_bf16(const float* __restrict__ in, bf16* __restrict__ out) {
  const int i = (blockIdx.x * 256 + threadIdx.x) * 4;
  const float4 v = *(const float4*)(in + i);
  out[i + 0] = __float2bfloat16(v.x);
  out[i + 1] = __float2bfloat16(v.y);
  out[i + 2] = __float2bfloat16(v.z);
  out[i + 3] = __float2bfloat16(v.w);
}

// ---------------------------------------------------------------------------
// RoPE cos/sin table: ctab[s*32 + i] = (cos, sin) of s * 10000^(-i/32).
// r5 lesson: cosf/sinf inside a register-heavy GEMM epilogue compile to
// __ocml CALLS -> caller-save spills of the whole accumulator (1.8 GB
// scratch traffic, 6x kernel slowdown). Trig lives ONLY in this tiny
// standalone kernel; consumers do table lookups.
// ---------------------------------------------------------------------------
__global__ void rope_tab_kernel(float2* __restrict__ ctab) {
  const int idx = blockIdx.x * 256 + threadIdx.x;   // 65536 entries
  const int i = idx & 31;
  const int s = idx >> 5;
  const float inv = fast_exp2(-(float)i * 0.41524101186092029f); // 10000^(-i/32)
  const float ang = (float)s * inv;
  ctab[idx] = make_float2(cosf(ang), sinf(ang));
}

// ---------------------------------------------------------------------------
// All 8 weight transposes (fp32 [R][C] -> bf16 [C][R]) in ONE kernel.
// ---------------------------------------------------------------------------
struct PrepArgs {
  const float* src[8];
  bf16* dst[8];
  int R[8], C[8], cum[8];
};

__global__ void prep_kernel(PrepArgs a) {
  __shared__ bf16 t[32][33];
  const int blk = blockIdx.x;
  int e = 0;
  while (e < 7 && blk >= a.cum[e]) ++e;
  const int lt = blk - (e ? a.cum[e - 1] : 0);
  const int R = a.R[e], C = a.C[e];
  const int tpr = C >> 5;
  const int bx = lt % tpr, by = lt / tpr;
  const float* in = a.src[e];
  bf16* out = a.dst[e];
  const int c0 = bx * 32, r0 = by * 32;
  const int tx = threadIdx.x, ty = threadIdx.y;
  for (int i = 0; i < 4; ++i)
    t[ty + 8 * i][tx] = __float2bfloat16(in[(size_t)(r0 + ty + 8 * i) * C + c0 + tx]);
  __syncthreads();
  for (int i = 0; i < 4; ++i)
    out[(size_t)(c0 + ty + 8 * i) * R + r0 + tx] = t[tx][ty + 8 * i];
}

// ---------------------------------------------------------------------------
// Generic bf16 GEMM, C = A @ B with B supplied transposed (Bt[N][K]).
// m97 structure. MODE compile-time.
// MODE 4: cn<1024 -> latcat; cn>=1024 -> k_rope with RoPE fused via ctab
// lookup (rope pair (i,i+32) = acc tiles (nt,nt+2) same lane; n0>=1024 is
// block-uniform; i0=l16, i1=16+l16, s=row&2047).
// ---------------------------------------------------------------------------
template <typename CT, int MODE>
__global__ void gemm_bt(const bf16* __restrict__ A, int lda,
                        const bf16* __restrict__ Bt,
                        CT* __restrict__ C, bf16* __restrict__ C2, int ldc,
                        int K, const float2* __restrict__ ctab)
{
  __shared__ __align__(16) bf16 As[128 * 32];
  __shared__ __align__(16) bf16 Bs[128 * 32];
  const int tid  = threadIdx.x;
  const int wave = tid >> 6, lane = tid & 63;
  const int quad = lane >> 4, l16 = lane & 15;
  const int m0 = blockIdx.y * 128, n0 = blockIdx.x * 128;
  const int wm = (wave >> 1) * 64, wn = (wave & 1) * 64;

  f32x4 acc[4][4];
#pragma unroll
  for (int i = 0; i < 4; ++i)
#pragma unroll
    for (int j = 0; j < 4; ++j) acc[i][j] = (f32x4){0.f, 0.f, 0.f, 0.f};

  const int r1  = tid >> 2;
  const int ks1 = (tid & 3) * 8;

  for (int k0 = 0; k0 < K; k0 += 32) {
    gload_lds16(A  + (size_t)(m0 + r1)      * lda + k0 + ks1, &As[tid * 8]);
    gload_lds16(A  + (size_t)(m0 + r1 + 64) * lda + k0 + ks1, &As[(tid + 256) * 8]);
    gload_lds16(Bt + (size_t)(n0 + r1)      * K   + k0 + ks1, &Bs[tid * 8]);
    gload_lds16(Bt + (size_t)(n0 + r1 + 64) * K   + k0 + ks1, &Bs[(tid + 256) * 8]);
    __syncthreads();

    short8 af[4], bf_[4];
#pragma unroll
    for (int mt = 0; mt < 4; ++mt)
      af[mt] = *(const short8*)&As[(wm + mt * 16 + l16) * 32 + quad * 8];
#pragma unroll
    for (int nt = 0; nt < 4; ++nt)
      bf_[nt] = *(const short8*)&Bs[(wn + nt * 16 + l16) * 32 + quad * 8];
#pragma unroll
    for (int mt = 0; mt < 4; ++mt)
#pragma unroll
      for (int nt = 0; nt < 4; ++nt)
        acc[mt][nt] = __builtin_amdgcn_mfma_f32_16x16x32_bf16(af[mt], bf_[nt], acc[mt][nt], 0, 0, 0);
    __syncthreads();
  }

  if (MODE == 0) {
#pragma unroll
    for (int mt = 0; mt < 4; ++mt) {
      const int row = m0 + wm + mt * 16 + quad * 4;
#pragma unroll
      for (int nt = 0; nt < 4; ++nt) {
        const int cn = n0 + wn + nt * 16 + l16;
        const f32x4 v = acc[mt][nt];
#pragma unroll
        for (int r = 0; r < 4; ++r)
          store_c(C, (size_t)(row + r) * ldc + cn, v[r]);
      }
    }
  } else if (MODE == 4) {
    if (n0 < 1024) {
      // latcat path (whole block has cn < 1024)
#pragma unroll
      for (int mt = 0; mt < 4; ++mt) {
        const int row = m0 + wm + mt * 16 + quad * 4;
#pragma unroll
        for (int nt = 0; nt < 4; ++nt) {
          const int cn = n0 + wn + nt * 16 + l16;
          const f32x4 v = acc[mt][nt];
#pragma unroll
          for (int r = 0; r < 4; ++r)
            store_c(C, (size_t)(row + r) * 1024 + cn, v[r]);
        }
      }
    } else {
      // k_rope path: RoPE via table lookup (no trig calls -> no spills)
#pragma unroll
      for (int mt = 0; mt < 4; ++mt) {
        const int row = m0 + wm + mt * 16 + quad * 4;
        f32x4 w[4];
#pragma unroll
        for (int nt = 0; nt < 4; ++nt) w[nt] = acc[mt][nt];
#pragma unroll
        for (int r = 0; r < 4; ++r) {
          const int s = (row + r) & 2047;
          const float2 cs0 = ctab[(s << 5) + l16];
          const float2 cs1 = ctab[(s << 5) + 16 + l16];
          const float x1a = w[0][r], x2a = w[2][r];
          const float x1b = w[1][r], x2b = w[3][r];
          w[0][r] = x1a * cs0.x - x2a * cs0.y;
          w[2][r] = x2a * cs0.x + x1a * cs0.y;
          w[1][r] = x1b * cs1.x - x2b * cs1.y;
          w[3][r] = x2b * cs1.x + x1b * cs1.y;
        }
#pragma unroll
        for (int nt = 0; nt < 4; ++nt) {
          const int cn2 = n0 + wn + nt * 16 + l16 - 1024;
          const int g = ((cn2 >> 6) << 7) + 64 + (cn2 & 63);
#pragma unroll
          for (int r = 0; r < 4; ++r)
            C2[(size_t)(row + r) * 2048 + g] = __float2bfloat16(w[nt][r]);
        }
      }
    }
  }
}

// ---------------------------------------------------------------------------
// Fused up-projection GEMM: k_nope+vT (N=3072, from kv_latent) and
// q-interleave (N=2048, from q_latent) in ONE launch. K=512, lda=1024.
// grid = (40, 32): x<24 -> k_nope/vT, x>=24 -> q-interleave.
// q_rope (n0>=1024 blocks of is2) gets RoPE fused via ctab lookup.
// ---------------------------------------------------------------------------
__global__ void gemm_up_fused(const bf16* __restrict__ latcat,
                              const bf16* __restrict__ wtUP,
                              const bf16* __restrict__ wtQcat,
                              bf16* __restrict__ vT, bf16* __restrict__ kfull,
                              bf16* __restrict__ qfull,
                              const float2* __restrict__ ctab)
{
  const bool is2 = (blockIdx.x >= 24);
  const bf16* A  = latcat + (is2 ? 512 : 0);
  const bf16* Bt = is2 ? wtQcat : wtUP;
  const int n0 = (is2 ? (int)blockIdx.x - 24 : (int)blockIdx.x) * 128;
  const int K = 512, lda = 1024;

  __shared__ __align__(16) bf16 As[128 * 32];
  __shared__ __align__(16) bf16 Bs[128 * 32];
  const int tid  = threadIdx.x;
  const int wave = tid >> 6, lane = tid & 63;
  const int quad = lane >> 4, l16 = lane & 15;
  const int m0 = blockIdx.y * 128;
  const int wm = (wave >> 1) * 64, wn = (wave & 1) * 64;

  f32x4 acc[4][4];
#pragma unroll
  for (int i = 0; i < 4; ++i)
#pragma unroll
    for (int j = 0; j < 4; ++j) acc[i][j] = (f32x4){0.f, 0.f, 0.f, 0.f};

  const int r1  = tid >> 2;
  const int ks1 = (tid & 3) * 8;

  for (int k0 = 0; k0 < K; k0 += 32) {
    gload_lds16(A  + (size_t)(m0 + r1)      * lda + k0 + ks1, &As[tid * 8]);
    gload_lds16(A  + (size_t)(m0 + r1 + 64) * lda + k0 + ks1, &As[(tid + 256) * 8]);
    gload_lds16(Bt + (size_t)(n0 + r1)      * K   + k0 + ks1, &Bs[tid * 8]);
    gload_lds16(Bt + (size_t)(n0 + r1 + 64) * K   + k0 + ks1, &Bs[(tid + 256) * 8]);
    __syncthreads();

    short8 af[4], bf_[4];
#pragma unroll
    for (int mt = 0; mt < 4; ++mt)
      af[mt] = *(const short8*)&As[(wm + mt * 16 + l16) * 32 + quad * 8];
#pragma unroll
    for (int nt = 0; nt < 4; ++nt)
      bf_[nt] = *(const short8*)&Bs[(wn + nt * 16 + l16) * 32 + quad * 8];
#pragma unroll
    for (int mt = 0; mt < 4; ++mt)
#pragma unroll
      for (int nt = 0; nt < 4; ++nt)
        acc[mt][nt] = __builtin_amdgcn_mfma_f32_16x16x32_bf16(af[mt], bf_[nt], acc[mt][nt], 0, 0, 0);
    __syncthreads();
  }

  if (is2) {
    if (n0 < 1024) {
      // q_nope half: plain interleave store
#pragma unroll
      for (int mt = 0; mt < 4; ++mt) {
        const int row = m0 + wm + mt * 16 + quad * 4;
#pragma unroll
        for (int nt = 0; nt < 4; ++nt) {
          const int cn = n0 + wn + nt * 16 + l16;
          const int g = (((cn >> 6) & 15) << 7) + ((cn >> 10) << 6) + (cn & 63);
          const f32x4 v = acc[mt][nt];
#pragma unroll
          for (int r = 0; r < 4; ++r)
            qfull[(size_t)(row + r) * 2048 + g] = __float2bfloat16(v[r]);
        }
      }
    } else {
      // q_rope half: RoPE via table lookup, then interleave store
#pragma unroll
      for (int mt = 0; mt < 4; ++mt) {
        const int row = m0 + wm + mt * 16 + quad * 4;
        f32x4 w[4];
#pragma unroll
        for (int nt = 0; nt < 4; ++nt) w[nt] = acc[mt][nt];
#pragma unroll
        for (int r = 0; r < 4; ++r) {
          const int s = (row + r) & 2047;
          const float2 cs0 = ctab[(s << 5) + l16];
          const float2 cs1 = ctab[(s << 5) + 16 + l16];
          const float x1a = w[0][r], x2a = w[2][r];
          const float x1b = w[1][r], x2b = w[3][r];
          w[0][r] = x1a * cs0.x - x2a * cs0.y;
          w[2][r] = x2a * cs0.x + x1a * cs0.y;
          w[1][r] = x1b * cs1.x - x2b * cs1.y;
          w[3][r] = x2b * cs1.x + x1b * cs1.y;
        }
#pragma unroll
        for (int nt = 0; nt < 4; ++nt) {
          const int cn = n0 + wn + nt * 16 + l16;
          const int g = (((cn >> 6) & 15) << 7) + ((cn >> 10) << 6) + (cn & 63);
#pragma unroll
          for (int r = 0; r < 4; ++r)
            qfull[(size_t)(row + r) * 2048 + g] = __float2bfloat16(w[nt][r]);
        }
      }
    }
  } else {
#pragma unroll
    for (int mt = 0; mt < 4; ++mt) {
      const int row = m0 + wm + mt * 16 + quad * 4;
#pragma unroll
      for (int nt = 0; nt < 4; ++nt) {
        const int cn = n0 + wn + nt * 16 + l16;
        const f32x4 v = acc[mt][nt];
        if (cn < 1024) {
          const int g = ((cn >> 6) << 7) + (cn & 63);
#pragma unroll
          for (int r = 0; r < 4; ++r)
            kfull[(size_t)(row + r) * 2048 + g] = __float2bfloat16(v[r]);
        } else {
          const int cn2 = cn - 1024;
          const int bb = row >> 11, s0 = row & 2047;
          b16x4 pk;
          pk.a = __float2bfloat16(v[0]); pk.b = __float2bfloat16(v[1]);
          pk.c = __float2bfloat16(v[2]); pk.d = __float2bfloat16(v[3]);
          *(b16x4*)(vT + ((size_t)(bb * 2048 + cn2)) * 2048 + s0) = pk;
        }
      }
    }
  }
}

// ---------------------------------------------------------------------------
// Flash attention v7 (causal) — r1 version (best measured: 68.4 us).
// 32 q-rows per wave (128-q blocks), 64-key tiles, XOR-swizzled K/V/P LDS,
// register prefetch, 2 barriers/tile. Grid (32 bh, 16 qt) = 512 blocks.
// ---------------------------------------------------------------------------
__global__ __launch_bounds__(256, 2) void attn7_kernel(
    const bf16* __restrict__ Q, const bf16* __restrict__ Kf,
    const bf16* __restrict__ VT, bf16* __restrict__ Y)
{
  __shared__ __align__(16) bf16 Ks[64 * 128];    // [key][d], XOR-swizzled
  __shared__ __align__(16) bf16 VTs[128 * 64];   // [d][key], XOR-swizzled
  __shared__ __align__(16) bf16 Ps[4 * 32 * 64]; // per-wave P, quad-XOR-swizzled
  const int tid  = threadIdx.x;
  const int wave = tid >> 6, lane = tid & 63;
  const int quad = lane >> 4, l16 = lane & 15;
  const int bh = blockIdx.x;                     // fastest-varying -> L2 locality
  const int yy = blockIdx.y;
  const int aa = yy & 7;
  const int qt = (yy >> 3) ? (15 - aa) : aa;
  const size_t kqbase = ((size_t)(bh >> 4) * 2048) * 2048 + (bh & 15) * 128;
  const size_t vtbase = (size_t)bh * 128 * 2048;
  const float C2 = 0.08838834764831845f * 1.4426950408889634f; // scale*log2e
  const float MNEG = -30.0f;

  short8 ones;
#pragma unroll
  for (int i = 0; i < 8; ++i) ones[i] = (short)0x3F80;   // bf16 1.0

  const int krow = tid >> 4, kcol = (tid & 15) * 8;  // K: 4 instr x 16 rows
  const int vrow = tid >> 3, vcol = (tid & 7) * 8;   // VT: 4 instr x 32 rows

  const int q0 = qt * 128;
  const int T = 2 * qt + 2;
  const int wq0 = q0 + wave * 32;                // this wave's first q row
  const int psbase = wave * (32 * 64);

  short8 qf[2][4];
#pragma unroll
  for (int m = 0; m < 2; ++m) {
    const bf16* qp = Q + kqbase + (size_t)(wq0 + m * 16 + l16) * 2048 + quad * 8;
#pragma unroll
    for (int kc = 0; kc < 4; ++kc) qf[m][kc] = *(const short8*)(qp + kc * 32);
  }
  f32x4 o[2][8];
#pragma unroll
  for (int m = 0; m < 2; ++m)
#pragma unroll
    for (int i = 0; i < 8; ++i) o[m][i] = (f32x4){0, 0, 0, 0};
  f32x4 lacc[2];
  lacc[0] = (f32x4){0, 0, 0, 0};
  lacc[1] = (f32x4){0, 0, 0, 0};

  short8 kg[4], vg[4];
#pragma unroll
  for (int i = 0; i < 4; ++i)
    kg[i] = *(const short8*)(Kf + kqbase + (size_t)(krow + i * 16) * 2048 + kcol);
#pragma unroll
  for (int i = 0; i < 4; ++i)
    vg[i] = *(const short8*)(VT + vtbase + (size_t)(vrow + i * 32) * 2048 + vcol);

  for (int t = 0; t < T; ++t) {
    const int k0 = t * 64;
    __syncthreads();                    // all waves done reading prev tile
#pragma unroll
    for (int i = 0; i < 4; ++i) {
      const int rw = krow + i * 16;
      *(short8*)&Ks[rw * 128 + (kcol ^ ((rw & 7) * 8))] = kg[i];
    }
#pragma unroll
    for (int i = 0; i < 4; ++i) {
      const int rw = vrow + i * 32;
      *(short8*)&VTs[rw * 64 + (vcol ^ ((rw & 7) * 8))] = vg[i];
    }
    __syncthreads();                    // tile t visible
    if (t + 1 < T) {                    // prefetch t+1 under compute
      const int kn = k0 + 64;
#pragma unroll
      for (int i = 0; i < 4; ++i)
        kg[i] = *(const short8*)(Kf + kqbase + (size_t)(kn + krow + i * 16) * 2048 + kcol);
#pragma unroll
      for (int i = 0; i < 4; ++i)
        vg[i] = *(const short8*)(VT + vtbase + (size_t)(vrow + i * 32) * 2048 + kn + vcol);
    }

    if (k0 <= wq0 + 31) {               // wave has >=1 unmasked key this tile
      // ---- S = Q K^T (raw scores), both m-tiles share each K fragment ----
      f32x4 sf[2][4];
#pragma unroll
      for (int m = 0; m < 2; ++m)
#pragma unroll
        for (int kt = 0; kt < 4; ++kt) sf[m][kt] = (f32x4){0, 0, 0, 0};
#pragma unroll
      for (int kt = 0; kt < 4; ++kt) {
#pragma unroll
        for (int kc = 0; kc < 4; ++kc) {
          const short8 bfr = *(const short8*)&Ks[(kt * 16 + l16) * 128 +
                                                ((kc * 32 + quad * 8) ^ ((l16 & 7) * 8))];
          sf[0][kt] = __builtin_amdgcn_mfma_f32_16x16x32_bf16(qf[0][kc], bfr, sf[0][kt], 0, 0, 0);
          sf[1][kt] = __builtin_amdgcn_mfma_f32_16x16x32_bf16(qf[1][kc], bfr, sf[1][kt], 0, 0, 0);
        }
      }
      // ---- causal mask (only near the diagonal) ----
#pragma unroll
      for (int m = 0; m < 2; ++m) {
        const int row0m = wq0 + m * 16 + quad * 4;
        if (k0 + 63 > row0m) {
#pragma unroll
          for (int kt = 0; kt < 4; ++kt) {
            const int col = k0 + kt * 16 + l16;
#pragma unroll
            for (int r = 0; r < 4; ++r)
              sf[m][kt][r] = (col > row0m + r) ? -3e38f : sf[m][kt][r];
          }
        }
      }
      // ---- p = exp2(s*C2 - M) -> Ps (quad-XOR swizzle: conflict-free) ----
#pragma unroll
      for (int m = 0; m < 2; ++m)
#pragma unroll
        for (int kt = 0; kt < 4; ++kt)
#pragma unroll
          for (int r = 0; r < 4; ++r) {
            const float p = fast_exp2(__builtin_fmaf(sf[m][kt][r], C2, MNEG));
            const int prow = m * 16 + quad * 4 + r;
            const int pcol = (kt * 16 + l16) ^ (quad * 16);
            Ps[psbase + prow * 64 + pcol] = __float2bfloat16(p);
          }
      asm volatile("s_waitcnt lgkmcnt(0)" ::: "memory");
      // ---- O += P V, l += P*1; each V fragment shared by both m-tiles ----
#pragma unroll
      for (int kc = 0; kc < 2; ++kc) {
        short8 ap[2];
#pragma unroll
        for (int m = 0; m < 2; ++m) {
          const int acol = (kc * 32 + quad * 8) ^ (((l16 >> 2) & 3) * 16);
          ap[m] = *(const short8*)&Ps[psbase + (m * 16 + l16) * 64 + acol];
          lacc[m] = __builtin_amdgcn_mfma_f32_16x16x32_bf16(ap[m], ones, lacc[m], 0, 0, 0);
        }
#pragma unroll
        for (int dt = 0; dt < 8; ++dt) {
          const short8 vb = *(const short8*)&VTs[(dt * 16 + l16) * 64 +
                                                ((kc * 32 + quad * 8) ^ ((l16 & 7) * 8))];
          o[0][dt] = __builtin_amdgcn_mfma_f32_16x16x32_bf16(ap[0], vb, o[0][dt], 0, 0, 0);
          o[1][dt] = __builtin_amdgcn_mfma_f32_16x16x32_bf16(ap[1], vb, o[1][dt], 0, 0, 0);
        }
      }
    }
  }

#pragma unroll
  for (int m = 0; m < 2; ++m) {
    const int row0m = wq0 + m * 16 + quad * 4;
#pragma unroll
    for (int r = 0; r < 4; ++r) {
      const float inv = 1.0f / lacc[m][r];
#pragma unroll
      for (int dt = 0; dt < 8; ++dt)
        Y[kqbase + (size_t)(row0m + r) * 2048 + dt * 16 + l16] =
            __float2bfloat16(o[m][dt][r] * inv);
    }
  }
}

// ---------------------------------------------------------------------------
extern "C" void kernel_launch(void* const* d_in, const int* in_sizes, int n_in,
                              void* d_out, int out_size, void* d_ws, size_t ws_size,
                              hipStream_t stream)
{
  const float* x      = (const float*)d_in[0];
  const float* Wkvd   = (const float*)d_in[1];
  const float* Wqd    = (const float*)d_in[2];
  const float* Wku    = (const float*)d_in[3];
  const float* Wqu    = (const float*)d_in[4];
  const float* Wvu    = (const float*)d_in[5];
  const float* Wropek = (const float*)d_in[6];
  const float* Wropeq = (const float*)d_in[7];
  const float* Wo     = (const float*)d_in[8];

  char* ws = (char*)d_ws;
  size_t off = 0;
  auto alloc = [&](size_t elems) {
    bf16* p = (bf16*)(ws + off);
    off += ((elems * sizeof(bf16) + 255) & ~(size_t)255);
    return p;
  };
  // Region A — dead before attn; ybuf (16 MB) aliases it.
  bf16* wtX    = alloc((size_t)2048 * 2048); // Wkvd^T | Wqd^T | Wropek^T
  bf16* wtUP   = alloc((size_t)3072 * 512);  // Wku^T | Wvu^T
  bf16* wtQcat = alloc((size_t)2048 * 512);  // Wqu^T | Wropeq^T
  bf16* latcat = alloc((size_t)4096 * 1024);
  // end region A (21 MB)
  bf16* wt_o   = alloc((size_t)2048 * 2048);
  bf16* xbf    = alloc((size_t)4096 * 2048);
  bf16* qfull  = alloc((size_t)4096 * 2048);
  bf16* kfull  = alloc((size_t)4096 * 2048);
  float2* ctab = (float2*)alloc((size_t)65536 * 4);  // 512 KB cos/sin table
  bf16* ybuf   = (bf16*)ws;
  bf16* vT     = (bf16*)d_out;
  (void)ws_size; (void)in_sizes; (void)n_in; (void)out_size;

  rope_tab_kernel<<<256, 256, 0, stream>>>(ctab);
  cvt_f32_bf16<<<8192, 256, 0, stream>>>(x, xbf);

  PrepArgs pa;
  const float* srcs[8] = {Wkvd, Wqd, Wropek, Wku, Wvu, Wqu, Wropeq, Wo};
  bf16* dsts[8] = {wtX, wtX + (size_t)512 * 2048, wtX + (size_t)1024 * 2048,
                   wtUP, wtUP + (size_t)1024 * 512,
                   wtQcat, wtQcat + (size_t)1024 * 512, wt_o};
  const int Rs[8] = {2048, 2048, 2048, 512, 512, 512, 512, 2048};
  const int Cs[8] = {512, 512, 1024, 1024, 2048, 1024, 1024, 2048};
  int cum = 0;
  for (int e = 0; e < 8; ++e) {
    pa.src[e] = srcs[e]; pa.dst[e] = dsts[e]; pa.R[e] = Rs[e]; pa.C[e] = Cs[e];
    cum += (Rs[e] >> 5) * (Cs[e] >> 5);
    pa.cum[e] = cum;
  }
  prep_kernel<<<cum, dim3(32, 8), 0, stream>>>(pa);

  // latcat = x @ [W_kv_d | W_q_d]  AND  k_rope = x @ W_rope_k (RoPE fused)
  gemm_bt<bf16, 4><<<dim3(16, 32), 256, 0, stream>>>(xbf, 2048, wtX, latcat, kfull, 1024, 2048, ctab);
  // k_nope+vT AND q-interleave (q_rope RoPE fused), single launch
  gemm_up_fused<<<dim3(40, 32), 256, 0, stream>>>(latcat, wtUP, wtQcat, vT, kfull, qfull, ctab);

  attn7_kernel<<<dim3(32, 16), 256, 0, stream>>>(qfull, kfull, vT, ybuf);
  // out = y @ W_o (fp32 store)
  gemm_bt<float, 0><<<dim3(16, 32), 256, 0, stream>>>(ybuf, 2048, wt_o, (float*)d_out, (bf16*)nullptr, 2048, 2048, ctab);
}

// Round 7
// 324.096 us; speedup vs baseline: 2.4685x; 1.0088x over previous
//
#include <hip/hip_runtime.h>
#include <hip/hip_bf16.h>

typedef __hip_bfloat16 bf16;
typedef __attribute__((ext_vector_type(8))) short short8;
typedef __attribute__((ext_vector_type(4))) float f32x4;

#define AS1 __attribute__((address_space(1)))
#define AS3 __attribute__((address_space(3)))

__device__ __forceinline__ void gload_lds16(const bf16* gp, bf16* lp) {
  __builtin_amdgcn_global_load_lds((const AS1 void*)gp, (AS3 void*)lp, 16, 0, 0);
}

__device__ __forceinline__ float fast_exp2(float x) {
#if __has_builtin(__builtin_amdgcn_exp2f)
  return __builtin_amdgcn_exp2f(x);
#else
  return exp2f(x);
#endif
}

__device__ __forceinline__ void store_c(bf16* C, size_t idx, float v) { C[idx] = __float2bfloat16(v); }
__device__ __forceinline__ void store_c(float* C, size_t idx, float v) { C[idx] = v; }

struct __align__(8) b16x4 { bf16 a, b, c, d; };

// ---------------------------------------------------------------------------
// fp32 -> bf16 elementwise convert (n multiple of 1024)
// ---------------------------------------------------------------------------
__global__ void cvt_f32_bf16(const float* __restrict__ in, bf16* __restrict__ out) {
  const int i = (blockIdx.x * 256 + threadIdx.x) * 4;
  const float4 v = *(const float4*)(in + i);
  out[i + 0] = __float2bfloat16(v.x);
  out[i + 1] = __float2bfloat16(v.y);
  out[i + 2] = __float2bfloat16(v.z);
  out[i + 3] = __float2bfloat16(v.w);
}

// ---------------------------------------------------------------------------
// RoPE cos/sin table: ctab[s*32 + i] = (cos, sin) of s * 10000^(-i/32).
// r5 lesson: trig calls ONLY in this tiny kernel (ocml calls in a
// register-heavy epilogue -> caller-save spill storm, 1.8 GB scratch).
// ---------------------------------------------------------------------------
__global__ void rope_tab_kernel(float2* __restrict__ ctab) {
  const int idx = blockIdx.x * 256 + threadIdx.x;   // 65536 entries
  const int i = idx & 31;
  const int s = idx >> 5;
  const float inv = fast_exp2(-(float)i * 0.41524101186092029f); // 10000^(-i/32)
  const float ang = (float)s * inv;
  ctab[idx] = make_float2(cosf(ang), sinf(ang));
}

// ---------------------------------------------------------------------------
// All 8 weight transposes (fp32 [R][C] -> bf16 [C][R]) in ONE kernel.
// ---------------------------------------------------------------------------
struct PrepArgs {
  const float* src[8];
  bf16* dst[8];
  int R[8], C[8], cum[8];
};

__global__ void prep_kernel(PrepArgs a) {
  __shared__ bf16 t[32][33];
  const int blk = blockIdx.x;
  int e = 0;
  while (e < 7 && blk >= a.cum[e]) ++e;
  const int lt = blk - (e ? a.cum[e - 1] : 0);
  const int R = a.R[e], C = a.C[e];
  const int tpr = C >> 5;
  const int bx = lt % tpr, by = lt / tpr;
  const float* in = a.src[e];
  bf16* out = a.dst[e];
  const int c0 = bx * 32, r0 = by * 32;
  const int tx = threadIdx.x, ty = threadIdx.y;
  for (int i = 0; i < 4; ++i)
    t[ty + 8 * i][tx] = __float2bfloat16(in[(size_t)(r0 + ty + 8 * i) * C + c0 + tx]);
  __syncthreads();
  for (int i = 0; i < 4; ++i)
    out[(size_t)(c0 + ty + 8 * i) * R + r0 + tx] = t[tx][ty + 8 * i];
}

// ---------------------------------------------------------------------------
// Generic bf16 GEMM, C = A @ B with B supplied transposed (Bt[N][K]).
// r6: T3-minimum double-buffered staging. At N=2048 the grid is 512 blocks
// = 2/CU; the m97 serial stage->barrier->compute chain is latency-exposed
// (m102 shape curve: N=2048 -> 320 TF). Issue next tile's global_load_lds
// BEFORE computing current, wait vmcnt(4) (prefetch stays in flight), raw
// s_barrier both sides (NOT __syncthreads - it drains vmcnt to 0).
// MODE 4: cn<1024 -> latcat; cn>=1024 -> k_rope with RoPE fused via ctab.
// ---------------------------------------------------------------------------
template <typename CT, int MODE>
__global__ void gemm_bt(const bf16* __restrict__ A, int lda,
                        const bf16* __restrict__ Bt,
                        CT* __restrict__ C, bf16* __restrict__ C2, int ldc,
                        int K, const float2* __restrict__ ctab)
{
  __shared__ __align__(16) bf16 As[2][128 * 32];
  __shared__ __align__(16) bf16 Bs[2][128 * 32];
  const int tid  = threadIdx.x;
  const int wave = tid >> 6, lane = tid & 63;
  const int quad = lane >> 4, l16 = lane & 15;
  const int m0 = blockIdx.y * 128, n0 = blockIdx.x * 128;
  const int wm = (wave >> 1) * 64, wn = (wave & 1) * 64;

  f32x4 acc[4][4];
#pragma unroll
  for (int i = 0; i < 4; ++i)
#pragma unroll
    for (int j = 0; j < 4; ++j) acc[i][j] = (f32x4){0.f, 0.f, 0.f, 0.f};

  const int r1  = tid >> 2;
  const int ks1 = (tid & 3) * 8;

  // prologue: stage tile 0 into buffer 0
  gload_lds16(A  + (size_t)(m0 + r1)      * lda + ks1, &As[0][tid * 8]);
  gload_lds16(A  + (size_t)(m0 + r1 + 64) * lda + ks1, &As[0][(tid + 256) * 8]);
  gload_lds16(Bt + (size_t)(n0 + r1)      * K   + ks1, &Bs[0][tid * 8]);
  gload_lds16(Bt + (size_t)(n0 + r1 + 64) * K   + ks1, &Bs[0][(tid + 256) * 8]);

  int cur = 0;
  for (int k0 = 0; k0 < K; k0 += 32) {
    if (k0 + 32 < K) {                  // prefetch next tile into buf^1
      const int kn = k0 + 32;
      const int nxt = cur ^ 1;
      gload_lds16(A  + (size_t)(m0 + r1)      * lda + kn + ks1, &As[nxt][tid * 8]);
      gload_lds16(A  + (size_t)(m0 + r1 + 64) * lda + kn + ks1, &As[nxt][(tid + 256) * 8]);
      gload_lds16(Bt + (size_t)(n0 + r1)      * K   + kn + ks1, &Bs[nxt][tid * 8]);
      gload_lds16(Bt + (size_t)(n0 + r1 + 64) * K   + kn + ks1, &Bs[nxt][(tid + 256) * 8]);
      asm volatile("s_waitcnt vmcnt(4)" ::: "memory");   // current tile done
    } else {
      asm volatile("s_waitcnt vmcnt(0)" ::: "memory");   // tail: drain
    }
    __builtin_amdgcn_s_barrier();       // all waves' current-tile loads visible

    short8 af[4], bf_[4];
#pragma unroll
    for (int mt = 0; mt < 4; ++mt)
      af[mt] = *(const short8*)&As[cur][(wm + mt * 16 + l16) * 32 + quad * 8];
#pragma unroll
    for (int nt = 0; nt < 4; ++nt)
      bf_[nt] = *(const short8*)&Bs[cur][(wn + nt * 16 + l16) * 32 + quad * 8];
#pragma unroll
    for (int mt = 0; mt < 4; ++mt)
#pragma unroll
      for (int nt = 0; nt < 4; ++nt)
        acc[mt][nt] = __builtin_amdgcn_mfma_f32_16x16x32_bf16(af[mt], bf_[nt], acc[mt][nt], 0, 0, 0);
    __builtin_amdgcn_s_barrier();       // done reading buf[cur]; re-stage ok
    cur ^= 1;
  }

  if (MODE == 0) {
#pragma unroll
    for (int mt = 0; mt < 4; ++mt) {
      const int row = m0 + wm + mt * 16 + quad * 4;
#pragma unroll
      for (int nt = 0; nt < 4; ++nt) {
        const int cn = n0 + wn + nt * 16 + l16;
        const f32x4 v = acc[mt][nt];
#pragma unroll
        for (int r = 0; r < 4; ++r)
          store_c(C, (size_t)(row + r) * ldc + cn, v[r]);
      }
    }
  } else if (MODE == 4) {
    if (n0 < 1024) {
      // latcat path (whole block has cn < 1024)
#pragma unroll
      for (int mt = 0; mt < 4; ++mt) {
        const int row = m0 + wm + mt * 16 + quad * 4;
#pragma unroll
        for (int nt = 0; nt < 4; ++nt) {
          const int cn = n0 + wn + nt * 16 + l16;
          const f32x4 v = acc[mt][nt];
#pragma unroll
          for (int r = 0; r < 4; ++r)
            store_c(C, (size_t)(row + r) * 1024 + cn, v[r]);
        }
      }
    } else {
      // k_rope path: RoPE via table lookup (no trig calls -> no spills)
#pragma unroll
      for (int mt = 0; mt < 4; ++mt) {
        const int row = m0 + wm + mt * 16 + quad * 4;
        f32x4 w[4];
#pragma unroll
        for (int nt = 0; nt < 4; ++nt) w[nt] = acc[mt][nt];
#pragma unroll
        for (int r = 0; r < 4; ++r) {
          const int s = (row + r) & 2047;
          const float2 cs0 = ctab[(s << 5) + l16];
          const float2 cs1 = ctab[(s << 5) + 16 + l16];
          const float x1a = w[0][r], x2a = w[2][r];
          const float x1b = w[1][r], x2b = w[3][r];
          w[0][r] = x1a * cs0.x - x2a * cs0.y;
          w[2][r] = x2a * cs0.x + x1a * cs0.y;
          w[1][r] = x1b * cs1.x - x2b * cs1.y;
          w[3][r] = x2b * cs1.x + x1b * cs1.y;
        }
#pragma unroll
        for (int nt = 0; nt < 4; ++nt) {
          const int cn2 = n0 + wn + nt * 16 + l16 - 1024;
          const int g = ((cn2 >> 6) << 7) + 64 + (cn2 & 63);
#pragma unroll
          for (int r = 0; r < 4; ++r)
            C2[(size_t)(row + r) * 2048 + g] = __float2bfloat16(w[nt][r]);
        }
      }
    }
  }
}

// ---------------------------------------------------------------------------
// Fused up-projection GEMM: k_nope+vT (N=3072, from kv_latent) and
// q-interleave (N=2048, from q_latent) in ONE launch. K=512, lda=1024.
// grid = (40, 32): x<24 -> k_nope/vT, x>=24 -> q-interleave.
// r6: same T3-minimum double-buffered staging as gemm_bt.
// ---------------------------------------------------------------------------
__global__ void gemm_up_fused(const bf16* __restrict__ latcat,
                              const bf16* __restrict__ wtUP,
                              const bf16* __restrict__ wtQcat,
                              bf16* __restrict__ vT, bf16* __restrict__ kfull,
                              bf16* __restrict__ qfull,
                              const float2* __restrict__ ctab)
{
  const bool is2 = (blockIdx.x >= 24);
  const bf16* A  = latcat + (is2 ? 512 : 0);
  const bf16* Bt = is2 ? wtQcat : wtUP;
  const int n0 = (is2 ? (int)blockIdx.x - 24 : (int)blockIdx.x) * 128;
  const int K = 512, lda = 1024;

  __shared__ __align__(16) bf16 As[2][128 * 32];
  __shared__ __align__(16) bf16 Bs[2][128 * 32];
  const int tid  = threadIdx.x;
  const int wave = tid >> 6, lane = tid & 63;
  const int quad = lane >> 4, l16 = lane & 15;
  const int m0 = blockIdx.y * 128;
  const int wm = (wave >> 1) * 64, wn = (wave & 1) * 64;

  f32x4 acc[4][4];
#pragma unroll
  for (int i = 0; i < 4; ++i)
#pragma unroll
    for (int j = 0; j < 4; ++j) acc[i][j] = (f32x4){0.f, 0.f, 0.f, 0.f};

  const int r1  = tid >> 2;
  const int ks1 = (tid & 3) * 8;

  gload_lds16(A  + (size_t)(m0 + r1)      * lda + ks1, &As[0][tid * 8]);
  gload_lds16(A  + (size_t)(m0 + r1 + 64) * lda + ks1, &As[0][(tid + 256) * 8]);
  gload_lds16(Bt + (size_t)(n0 + r1)      * K   + ks1, &Bs[0][tid * 8]);
  gload_lds16(Bt + (size_t)(n0 + r1 + 64) * K   + ks1, &Bs[0][(tid + 256) * 8]);

  int cur = 0;
  for (int k0 = 0; k0 < K; k0 += 32) {
    if (k0 + 32 < K) {
      const int kn = k0 + 32;
      const int nxt = cur ^ 1;
      gload_lds16(A  + (size_t)(m0 + r1)      * lda + kn + ks1, &As[nxt][tid * 8]);
      gload_lds16(A  + (size_t)(m0 + r1 + 64) * lda + kn + ks1, &As[nxt][(tid + 256) * 8]);
      gload_lds16(Bt + (size_t)(n0 + r1)      * K   + kn + ks1, &Bs[nxt][tid * 8]);
      gload_lds16(Bt + (size_t)(n0 + r1 + 64) * K   + kn + ks1, &Bs[nxt][(tid + 256) * 8]);
      asm volatile("s_waitcnt vmcnt(4)" ::: "memory");
    } else {
      asm volatile("s_waitcnt vmcnt(0)" ::: "memory");
    }
    __builtin_amdgcn_s_barrier();

    short8 af[4], bf_[4];
#pragma unroll
    for (int mt = 0; mt < 4; ++mt)
      af[mt] = *(const short8*)&As[cur][(wm + mt * 16 + l16) * 32 + quad * 8];
#pragma unroll
    for (int nt = 0; nt < 4; ++nt)
      bf_[nt] = *(const short8*)&Bs[cur][(wn + nt * 16 + l16) * 32 + quad * 8];
#pragma unroll
    for (int mt = 0; mt < 4; ++mt)
#pragma unroll
      for (int nt = 0; nt < 4; ++nt)
        acc[mt][nt] = __builtin_amdgcn_mfma_f32_16x16x32_bf16(af[mt], bf_[nt], acc[mt][nt], 0, 0, 0);
    __builtin_amdgcn_s_barrier();
    cur ^= 1;
  }

  if (is2) {
    if (n0 < 1024) {
      // q_nope half: plain interleave store
#pragma unroll
      for (int mt = 0; mt < 4; ++mt) {
        const int row = m0 + wm + mt * 16 + quad * 4;
#pragma unroll
        for (int nt = 0; nt < 4; ++nt) {
          const int cn = n0 + wn + nt * 16 + l16;
          const int g = (((cn >> 6) & 15) << 7) + ((cn >> 10) << 6) + (cn & 63);
          const f32x4 v = acc[mt][nt];
#pragma unroll
          for (int r = 0; r < 4; ++r)
            qfull[(size_t)(row + r) * 2048 + g] = __float2bfloat16(v[r]);
        }
      }
    } else {
      // q_rope half: RoPE via table lookup, then interleave store
#pragma unroll
      for (int mt = 0; mt < 4; ++mt) {
        const int row = m0 + wm + mt * 16 + quad * 4;
        f32x4 w[4];
#pragma unroll
        for (int nt = 0; nt < 4; ++nt) w[nt] = acc[mt][nt];
#pragma unroll
        for (int r = 0; r < 4; ++r) {
          const int s = (row + r) & 2047;
          const float2 cs0 = ctab[(s << 5) + l16];
          const float2 cs1 = ctab[(s << 5) + 16 + l16];
          const float x1a = w[0][r], x2a = w[2][r];
          const float x1b = w[1][r], x2b = w[3][r];
          w[0][r] = x1a * cs0.x - x2a * cs0.y;
          w[2][r] = x2a * cs0.x + x1a * cs0.y;
          w[1][r] = x1b * cs1.x - x2b * cs1.y;
          w[3][r] = x2b * cs1.x + x1b * cs1.y;
        }
#pragma unroll
        for (int nt = 0; nt < 4; ++nt) {
          const int cn = n0 + wn + nt * 16 + l16;
          const int g = (((cn >> 6) & 15) << 7) + ((cn >> 10) << 6) + (cn & 63);
#pragma unroll
          for (int r = 0; r < 4; ++r)
            qfull[(size_t)(row + r) * 2048 + g] = __float2bfloat16(w[nt][r]);
        }
      }
    }
  } else {
#pragma unroll
    for (int mt = 0; mt < 4; ++mt) {
      const int row = m0 + wm + mt * 16 + quad * 4;
#pragma unroll
      for (int nt = 0; nt < 4; ++nt) {
        const int cn = n0 + wn + nt * 16 + l16;
        const f32x4 v = acc[mt][nt];
        if (cn < 1024) {
          const int g = ((cn >> 6) << 7) + (cn & 63);
#pragma unroll
          for (int r = 0; r < 4; ++r)
            kfull[(size_t)(row + r) * 2048 + g] = __float2bfloat16(v[r]);
        } else {
          const int cn2 = cn - 1024;
          const int bb = row >> 11, s0 = row & 2047;
          b16x4 pk;
          pk.a = __float2bfloat16(v[0]); pk.b = __float2bfloat16(v[1]);
          pk.c = __float2bfloat16(v[2]); pk.d = __float2bfloat16(v[3]);
          *(b16x4*)(vT + ((size_t)(bb * 2048 + cn2)) * 2048 + s0) = pk;
        }
      }
    }
  }
}

// ---------------------------------------------------------------------------
// Flash attention v7 (causal) — r1 version (best measured: 68.4 us).
// 32 q-rows per wave (128-q blocks), 64-key tiles, XOR-swizzled K/V/P LDS,
// register prefetch, 2 barriers/tile. Grid (32 bh, 16 qt) = 512 blocks.
// ---------------------------------------------------------------------------
__global__ __launch_bounds__(256, 2) void attn7_kernel(
    const bf16* __restrict__ Q, const bf16* __restrict__ Kf,
    const bf16* __restrict__ VT, bf16* __restrict__ Y)
{
  __shared__ __align__(16) bf16 Ks[64 * 128];    // [key][d], XOR-swizzled
  __shared__ __align__(16) bf16 VTs[128 * 64];   // [d][key], XOR-swizzled
  __shared__ __align__(16) bf16 Ps[4 * 32 * 64]; // per-wave P, quad-XOR-swizzled
  const int tid  = threadIdx.x;
  const int wave = tid >> 6, lane = tid & 63;
  const int quad = lane >> 4, l16 = lane & 15;
  const int bh = blockIdx.x;                     // fastest-varying -> L2 locality
  const int yy = blockIdx.y;
  const int aa = yy & 7;
  const int qt = (yy >> 3) ? (15 - aa) : aa;
  const size_t kqbase = ((size_t)(bh >> 4) * 2048) * 2048 + (bh & 15) * 128;
  const size_t vtbase = (size_t)bh * 128 * 2048;
  const float C2 = 0.08838834764831845f * 1.4426950408889634f; // scale*log2e
  const float MNEG = -30.0f;

  short8 ones;
#pragma unroll
  for (int i = 0; i < 8; ++i) ones[i] = (short)0x3F80;   // bf16 1.0

  const int krow = tid >> 4, kcol = (tid & 15) * 8;  // K: 4 instr x 16 rows
  const int vrow = tid >> 3, vcol = (tid & 7) * 8;   // VT: 4 instr x 32 rows

  const int q0 = qt * 128;
  const int T = 2 * qt + 2;
  const int wq0 = q0 + wave * 32;                // this wave's first q row
  const int psbase = wave * (32 * 64);

  short8 qf[2][4];
#pragma unroll
  for (int m = 0; m < 2; ++m) {
    const bf16* qp = Q + kqbase + (size_t)(wq0 + m * 16 + l16) * 2048 + quad * 8;
#pragma unroll
    for (int kc = 0; kc < 4; ++kc) qf[m][kc] = *(const short8*)(qp + kc * 32);
  }
  f32x4 o[2][8];
#pragma unroll
  for (int m = 0; m < 2; ++m)
#pragma unroll
    for (int i = 0; i < 8; ++i) o[m][i] = (f32x4){0, 0, 0, 0};
  f32x4 lacc[2];
  lacc[0] = (f32x4){0, 0, 0, 0};
  lacc[1] = (f32x4){0, 0, 0, 0};

  short8 kg[4], vg[4];
#pragma unroll
  for (int i = 0; i < 4; ++i)
    kg[i] = *(const short8*)(Kf + kqbase + (size_t)(krow + i * 16) * 2048 + kcol);
#pragma unroll
  for (int i = 0; i < 4; ++i)
    vg[i] = *(const short8*)(VT + vtbase + (size_t)(vrow + i * 32) * 2048 + vcol);

  for (int t = 0; t < T; ++t) {
    const int k0 = t * 64;
    __syncthreads();                    // all waves done reading prev tile
#pragma unroll
    for (int i = 0; i < 4; ++i) {
      const int rw = krow + i * 16;
      *(short8*)&Ks[rw * 128 + (kcol ^ ((rw & 7) * 8))] = kg[i];
    }
#pragma unroll
    for (int i = 0; i < 4; ++i) {
      const int rw = vrow + i * 32;
      *(short8*)&VTs[rw * 64 + (vcol ^ ((rw & 7) * 8))] = vg[i];
    }
    __syncthreads();                    // tile t visible
    if (t + 1 < T) {                    // prefetch t+1 under compute
      const int kn = k0 + 64;
#pragma unroll
      for (int i = 0; i < 4; ++i)
        kg[i] = *(const short8*)(Kf + kqbase + (size_t)(kn + krow + i * 16) * 2048 + kcol);
#pragma unroll
      for (int i = 0; i < 4; ++i)
        vg[i] = *(const short8*)(VT + vtbase + (size_t)(vrow + i * 32) * 2048 + kn + vcol);
    }

    if (k0 <= wq0 + 31) {               // wave has >=1 unmasked key this tile
      // ---- S = Q K^T (raw scores), both m-tiles share each K fragment ----
      f32x4 sf[2][4];
#pragma unroll
      for (int m = 0; m < 2; ++m)
#pragma unroll
        for (int kt = 0; kt < 4; ++kt) sf[m][kt] = (f32x4){0, 0, 0, 0};
#pragma unroll
      for (int kt = 0; kt < 4; ++kt) {
#pragma unroll
        for (int kc = 0; kc < 4; ++kc) {
          const short8 bfr = *(const short8*)&Ks[(kt * 16 + l16) * 128 +
                                                ((kc * 32 + quad * 8) ^ ((l16 & 7) * 8))];
          sf[0][kt] = __builtin_amdgcn_mfma_f32_16x16x32_bf16(qf[0][kc], bfr, sf[0][kt], 0, 0, 0);
          sf[1][kt] = __builtin_amdgcn_mfma_f32_16x16x32_bf16(qf[1][kc], bfr, sf[1][kt], 0, 0, 0);
        }
      }
      // ---- causal mask (only near the diagonal) ----
#pragma unroll
      for (int m = 0; m < 2; ++m) {
        const int row0m = wq0 + m * 16 + quad * 4;
        if (k0 + 63 > row0m) {
#pragma unroll
          for (int kt = 0; kt < 4; ++kt) {
            const int col = k0 + kt * 16 + l16;
#pragma unroll
            for (int r = 0; r < 4; ++r)
              sf[m][kt][r] = (col > row0m + r) ? -3e38f : sf[m][kt][r];
          }
        }
      }
      // ---- p = exp2(s*C2 - M) -> Ps (quad-XOR swizzle: conflict-free) ----
#pragma unroll
      for (int m = 0; m < 2; ++m)
#pragma unroll
        for (int kt = 0; kt < 4; ++kt)
#pragma unroll
          for (int r = 0; r < 4; ++r) {
            const float p = fast_exp2(__builtin_fmaf(sf[m][kt][r], C2, MNEG));
            const int prow = m * 16 + quad * 4 + r;
            const int pcol = (kt * 16 + l16) ^ (quad * 16);
            Ps[psbase + prow * 64 + pcol] = __float2bfloat16(p);
          }
      asm volatile("s_waitcnt lgkmcnt(0)" ::: "memory");
      // ---- O += P V, l += P*1; each V fragment shared by both m-tiles ----
#pragma unroll
      for (int kc = 0; kc < 2; ++kc) {
        short8 ap[2];
#pragma unroll
        for (int m = 0; m < 2; ++m) {
          const int acol = (kc * 32 + quad * 8) ^ (((l16 >> 2) & 3) * 16);
          ap[m] = *(const short8*)&Ps[psbase + (m * 16 + l16) * 64 + acol];
          lacc[m] = __builtin_amdgcn_mfma_f32_16x16x32_bf16(ap[m], ones, lacc[m], 0, 0, 0);
        }
#pragma unroll
        for (int dt = 0; dt < 8; ++dt) {
          const short8 vb = *(const short8*)&VTs[(dt * 16 + l16) * 64 +
                                                ((kc * 32 + quad * 8) ^ ((l16 & 7) * 8))];
          o[0][dt] = __builtin_amdgcn_mfma_f32_16x16x32_bf16(ap[0], vb, o[0][dt], 0, 0, 0);
          o[1][dt] = __builtin_amdgcn_mfma_f32_16x16x32_bf16(ap[1], vb, o[1][dt], 0, 0, 0);
        }
      }
    }
  }

#pragma unroll
  for (int m = 0; m < 2; ++m) {
    const int row0m = wq0 + m * 16 + quad * 4;
#pragma unroll
    for (int r = 0; r < 4; ++r) {
      const float inv = 1.0f / lacc[m][r];
#pragma unroll
      for (int dt = 0; dt < 8; ++dt)
        Y[kqbase + (size_t)(row0m + r) * 2048 + dt * 16 + l16] =
            __float2bfloat16(o[m][dt][r] * inv);
    }
  }
}

// ---------------------------------------------------------------------------
extern "C" void kernel_launch(void* const* d_in, const int* in_sizes, int n_in,
                              void* d_out, int out_size, void* d_ws, size_t ws_size,
                              hipStream_t stream)
{
  const float* x      = (const float*)d_in[0];
  const float* Wkvd   = (const float*)d_in[1];
  const float* Wqd    = (const float*)d_in[2];
  const float* Wku    = (const float*)d_in[3];
  const float* Wqu    = (const float*)d_in[4];
  const float* Wvu    = (const float*)d_in[5];
  const float* Wropek = (const float*)d_in[6];
  const float* Wropeq = (const float*)d_in[7];
  const float* Wo     = (const float*)d_in[8];

  char* ws = (char*)d_ws;
  size_t off = 0;
  auto alloc = [&](size_t elems) {
    bf16* p = (bf16*)(ws + off);
    off += ((elems * sizeof(bf16) + 255) & ~(size_t)255);
    return p;
  };
  // Region A — dead before attn; ybuf (16 MB) aliases it.
  bf16* wtX    = alloc((size_t)2048 * 2048); // Wkvd^T | Wqd^T | Wropek^T
  bf16* wtUP   = alloc((size_t)3072 * 512);  // Wku^T | Wvu^T
  bf16* wtQcat = alloc((size_t)2048 * 512);  // Wqu^T | Wropeq^T
  bf16* latcat = alloc((size_t)4096 * 1024);
  // end region A (21 MB)
  bf16* wt_o   = alloc((size_t)2048 * 2048);
  bf16* xbf    = alloc((size_t)4096 * 2048);
  bf16* qfull  = alloc((size_t)4096 * 2048);
  bf16* kfull  = alloc((size_t)4096 * 2048);
  float2* ctab = (float2*)alloc((size_t)65536 * 4);  // 512 KB cos/sin table
  bf16* ybuf   = (bf16*)ws;
  bf16* vT     = (bf16*)d_out;
  (void)ws_size; (void)in_sizes; (void)n_in; (void)out_size;

  rope_tab_kernel<<<256, 256, 0, stream>>>(ctab);
  cvt_f32_bf16<<<8192, 256, 0, stream>>>(x, xbf);

  PrepArgs pa;
  const float* srcs[8] = {Wkvd, Wqd, Wropek, Wku, Wvu, Wqu, Wropeq, Wo};
  bf16* dsts[8] = {wtX, wtX + (size_t)512 * 2048, wtX + (size_t)1024 * 2048,
                   wtUP, wtUP + (size_t)1024 * 512,
                   wtQcat, wtQcat + (size_t)1024 * 512, wt_o};
  const int Rs[8] = {2048, 2048, 2048, 512, 512, 512, 512, 2048};
  const int Cs[8] = {512, 512, 1024, 1024, 2048, 1024, 1024, 2048};
  int cum = 0;
  for (int e = 0; e < 8; ++e) {
    pa.src[e] = srcs[e]; pa.dst[e] = dsts[e]; pa.R[e] = Rs[e]; pa.C[e] = Cs[e];
    cum += (Rs[e] >> 5) * (Cs[e] >> 5);
    pa.cum[e] = cum;
  }
  prep_kernel<<<cum, dim3(32, 8), 0, stream>>>(pa);

  // latcat = x @ [W_kv_d | W_q_d]  AND  k_rope = x @ W_rope_k (RoPE fused)
  gemm_bt<bf16, 4><<<dim3(16, 32), 256, 0, stream>>>(xbf, 2048, wtX, latcat, kfull, 1024, 2048, ctab);
  // k_nope+vT AND q-interleave (q_rope RoPE fused), single launch
  gemm_up_fused<<<dim3(40, 32), 256, 0, stream>>>(latcat, wtUP, wtQcat, vT, kfull, qfull, ctab);

  attn7_kernel<<<dim3(32, 16), 256, 0, stream>>>(qfull, kfull, vT, ybuf);
  // out = y @ W_o (fp32 store)
  gemm_bt<float, 0><<<dim3(16, 32), 256, 0, stream>>>(ybuf, 2048, wt_o, (float*)d_out, (bf16*)nullptr, 2048, 2048, ctab);
}